// Round 5
// baseline (464.483 us; speedup 1.0000x reference)
//
#include <hip/hip_runtime.h>
#include <hip/hip_bf16.h>

typedef __hip_bfloat16 bf16;
typedef __attribute__((ext_vector_type(8))) short short8;
typedef __attribute__((ext_vector_type(4))) float floatx4;

#define GLD_LDS(g, l) __builtin_amdgcn_global_load_lds( \
    (const __attribute__((address_space(1))) void*)(g), \
    (__attribute__((address_space(3))) void*)(l), 16, 0, 0)

// Stage a [128][32] bf16 tile into LDS from an f32 row-major source.
// Thread t covers row t>>1, cols (t&1)*16 .. +15.
__device__ __forceinline__ void stage_f32(const float* __restrict__ src, int ld,
                                          bf16* lds, int t)
{
    const int sr = t >> 1;
    const int sc = (t & 1) * 16;
    const float* g = src + (long)sr * ld + sc;
    floatx4 f[4];
    #pragma unroll
    for (int i = 0; i < 4; ++i) f[i] = *(const floatx4*)(g + i * 4);
    short8 h[2];
    #pragma unroll
    for (int v = 0; v < 2; ++v)
        #pragma unroll
        for (int e = 0; e < 8; ++e) {
            union { bf16 b; short s; } u;
            u.b = __float2bfloat16(f[v * 2 + (e >> 2)][e & 3]);
            h[v][e] = u.s;
        }
    *(short8*)(lds + sr * 32 + sc)     = h[0];
    *(short8*)(lds + sr * 32 + sc + 8) = h[1];
}

// ---------------------------------------------------------------------------
// GEMM: C = A(MxK,row) * B^T (B is NxK row-major) + bias[col]
// 128x128 tile, BK=32, 4 waves (2x2 of 64x64), 16x16x32 bf16 MFMA.
// AF32/BF32: source dtype of A/B (f32 -> reg-stage+convert; bf16 -> GLD_LDS).
// EPI=0: QKV scatter epilogue (bf16 workspaces)
// EPI=1: f32 store to ((float*)o0)[r*N+col]   <-- d_out is FLOAT32
// ---------------------------------------------------------------------------
template<int EPI, int AF32, int BF32>
__global__ __launch_bounds__(256, 2)
void gemm_bt(const void* __restrict__ Ap, const void* __restrict__ Bp,
             const float* __restrict__ bias,
             void* __restrict__ o0, bf16* __restrict__ o1, bf16* __restrict__ o2,
             int K, int N)
{
    __shared__ __align__(16) bf16 lA[128 * 32];
    __shared__ __align__(16) bf16 lB[128 * 32];

    const int t    = threadIdx.x;
    const int lane = t & 63;
    const int w    = t >> 6;
    const int mBase = blockIdx.y * 128;
    const int nBase = blockIdx.x * 128;
    const int wr = (w >> 1) * 64;
    const int wc = (w & 1) * 64;

    // bf16 async-staging addresses (used when !AF32 / !BF32)
    const int rowL = t >> 2;            // 0..63 (+64)
    const int colL = (t & 3) * 8;
    const bf16* gA0 = (const bf16*)Ap + (long)(mBase + rowL) * K + colL;
    const bf16* gA1 = (const bf16*)Ap + (long)(mBase + rowL + 64) * K + colL;
    const bf16* gB0 = (const bf16*)Bp + (long)(nBase + rowL) * K + colL;
    const bf16* gB1 = (const bf16*)Bp + (long)(nBase + rowL + 64) * K + colL;
    char* lAb = (char*)lA + w * 1024;   // wave-uniform LDS base
    char* lBb = (char*)lB + w * 1024;

    floatx4 acc[4][4] = {};

    for (int k0 = 0; k0 < K; k0 += 32) {
        if constexpr (AF32) {
            stage_f32((const float*)Ap + (long)mBase * K + k0, K, lA, t);
        } else {
            GLD_LDS(gA0 + k0, lAb);
            GLD_LDS(gA1 + k0, lAb + 4096);
        }
        if constexpr (BF32) {
            stage_f32((const float*)Bp + (long)nBase * K + k0, K, lB, t);
        } else {
            GLD_LDS(gB0 + k0, lBb);
            GLD_LDS(gB1 + k0, lBb + 4096);
        }
        asm volatile("s_waitcnt vmcnt(0)" ::: "memory");
        __syncthreads();

        short8 af[4], bfr[4];
        #pragma unroll
        for (int m = 0; m < 4; ++m)
            af[m] = *(const short8*)(lA + (wr + m * 16 + (lane & 15)) * 32 + (lane >> 4) * 8);
        #pragma unroll
        for (int n = 0; n < 4; ++n)
            bfr[n] = *(const short8*)(lB + (wc + n * 16 + (lane & 15)) * 32 + (lane >> 4) * 8);
        #pragma unroll
        for (int m = 0; m < 4; ++m)
            #pragma unroll
            for (int n = 0; n < 4; ++n)
                acc[m][n] = __builtin_amdgcn_mfma_f32_16x16x32_bf16(af[m], bfr[n], acc[m][n], 0, 0, 0);
        __syncthreads();
    }

    // epilogue: C frag (m,n): row = (lane>>4)*4+j, col = lane&15
    #pragma unroll
    for (int m = 0; m < 4; ++m) {
        #pragma unroll
        for (int n = 0; n < 4; ++n) {
            const int col = nBase + wc + n * 16 + (lane & 15);
            const int r0  = mBase + wr + m * 16 + ((lane >> 4) << 2);
            const float bv = bias[col];
            if constexpr (EPI == 0) {
                const int h   = col / 192;
                const int rem = col % 192;
                const int qkv = rem >> 6;
                const int d   = rem & 63;
                bf16* dst = (qkv == 0) ? (bf16*)o0 : (qkv == 1) ? o1 : o2;
                #pragma unroll
                for (int j = 0; j < 4; ++j) {
                    const int r = r0 + j;
                    const int s = r >> 2;      // B=4
                    const int b = r & 3;
                    dst[(((((b << 4) + h) << 11) + s) << 6) + d] =
                        __float2bfloat16(acc[m][n][j] + bv);
                }
            } else {
                #pragma unroll
                for (int j = 0; j < 4; ++j)
                    ((float*)o0)[(long)(r0 + j) * N + col] = acc[m][n][j] + bv;
            }
        }
    }
}

// ---------------------------------------------------------------------------
// Flash attention, per (head, q-block of 128). 4 waves x 32 q-rows each.
// DIAGNOSTIC BUILD (kept): all LDS linear (no swizzles), reg-staged K/V,
// full __syncthreads around the P round-trip.
// ---------------------------------------------------------------------------
__global__ __launch_bounds__(256, 2)
void attn_kernel(const bf16* __restrict__ Q, const bf16* __restrict__ Kg,
                 const bf16* __restrict__ V, bf16* __restrict__ Ctx)
{
    __shared__ __align__(16) bf16 lK[64 * 64];
    __shared__ __align__(16) bf16 lV[64 * 64];
    __shared__ __align__(16) bf16 lVt[64 * 64];
    __shared__ __align__(16) bf16 lP[4][32 * 64];

    const int t    = threadIdx.x;
    const int lane = t & 63;
    const int w    = t >> 6;
    const int bh   = blockIdx.y;                 // b*16 + h
    const int q0   = blockIdx.x * 128 + w * 32;  // this wave's first q row
    const long hb  = (long)bh * 2048 * 64;
    const bf16* Qh = Q  + hb;
    const bf16* Kh = Kg + hb;
    const bf16* Vh = V  + hb;

    // Q fragments: rows q0 + m*16 + (lane&15), d = kk*32 + (lane>>4)*8
    short8 qf[2][2];
    #pragma unroll
    for (int m = 0; m < 2; ++m)
        #pragma unroll
        for (int kk = 0; kk < 2; ++kk)
            qf[m][kk] = *(const short8*)(Qh + (q0 + m * 16 + (lane & 15)) * 64
                                            + kk * 32 + (lane >> 4) * 8);

    floatx4 o[2][4] = {};
    float mrun[2][4], lrun[2][4];
    #pragma unroll
    for (int m = 0; m < 2; ++m)
        #pragma unroll
        for (int j = 0; j < 4; ++j) { mrun[m][j] = -1e30f; lrun[m][j] = 0.f; }

    const float cs = 0.125f * 1.44269504089f;    // scale * log2(e)
    short* lPw = (short*)lP[w];

    for (int t0 = 0; t0 < 2048; t0 += 64) {
        // ---- stage K,V (reg-staged, linear LDS) ----
        {
            const int off0 = t * 8;          // elements; thread covers 16B x2
            const int off1 = 2048 + t * 8;
            short8 k0 = *(const short8*)(Kh + t0 * 64 + off0);
            short8 k1 = *(const short8*)(Kh + t0 * 64 + off1);
            short8 v0 = *(const short8*)(Vh + t0 * 64 + off0);
            short8 v1 = *(const short8*)(Vh + t0 * 64 + off1);
            *(short8*)(lK + off0) = k0;
            *(short8*)(lK + off1) = k1;
            *(short8*)(lV + off0) = v0;
            *(short8*)(lV + off1) = v1;
        }
        __syncthreads();

        // ---- QK^T: S[q][key], B-operand rows = keys (linear lK) ----
        floatx4 sa[2][4] = {};
        short8 kf[4][2];
        #pragma unroll
        for (int n = 0; n < 4; ++n)
            #pragma unroll
            for (int kk = 0; kk < 2; ++kk) {
                const int key = n * 16 + (lane & 15);
                kf[n][kk] = *(const short8*)(lK + key * 64 + kk * 32 + (lane >> 4) * 8);
            }
        #pragma unroll
        for (int m = 0; m < 2; ++m)
            #pragma unroll
            for (int n = 0; n < 4; ++n)
                #pragma unroll
                for (int kk = 0; kk < 2; ++kk)
                    sa[m][n] = __builtin_amdgcn_mfma_f32_16x16x32_bf16(qf[m][kk], kf[n][kk], sa[m][n], 0, 0, 0);

        // ---- transpose V tile into lVt[dim][key] (linear) ----
        {
            const int key = t >> 2;
            const int d0  = (t & 3) << 4;
            short8 v0 = *(const short8*)(lV + key * 64 + d0);
            short8 v1 = *(const short8*)(lV + key * 64 + d0 + 8);
            short* base = (short*)lVt;
            #pragma unroll
            for (int e = 0; e < 8; ++e) {
                base[((d0 + e) << 6) + key]     = v0[e];
                base[((d0 + 8 + e) << 6) + key] = v1[e];
            }
        }
        __syncthreads();   // lVt ready; lK reads done

        // ---- online softmax (rows: m*16 + (lane>>4)*4 + j, over 64 keys) ----
        #pragma unroll
        for (int m = 0; m < 2; ++m)
            #pragma unroll
            for (int n = 0; n < 4; ++n)
                sa[m][n] *= cs;
        #pragma unroll
        for (int m = 0; m < 2; ++m)
            #pragma unroll
            for (int j = 0; j < 4; ++j) {
                float mx = fmaxf(fmaxf(sa[m][0][j], sa[m][1][j]),
                                 fmaxf(sa[m][2][j], sa[m][3][j]));
                mx = fmaxf(mx, __shfl_xor(mx, 1));
                mx = fmaxf(mx, __shfl_xor(mx, 2));
                mx = fmaxf(mx, __shfl_xor(mx, 4));
                mx = fmaxf(mx, __shfl_xor(mx, 8));
                const float mnew = fmaxf(mrun[m][j], mx);
                const float fac  = exp2f(mrun[m][j] - mnew);
                mrun[m][j] = mnew;
                float rs = 0.f;
                #pragma unroll
                for (int n = 0; n < 4; ++n) {
                    const float p = exp2f(sa[m][n][j] - mnew);
                    sa[m][n][j] = p;
                    rs += p;
                }
                rs += __shfl_xor(rs, 1);
                rs += __shfl_xor(rs, 2);
                rs += __shfl_xor(rs, 4);
                rs += __shfl_xor(rs, 8);
                lrun[m][j] = lrun[m][j] * fac + rs;
                #pragma unroll
                for (int n2 = 0; n2 < 4; ++n2)
                    o[m][n2][j] *= fac;
            }

        // ---- P -> per-wave LDS (C-layout scatter, linear) ----
        #pragma unroll
        for (int m = 0; m < 2; ++m)
            #pragma unroll
            for (int n = 0; n < 4; ++n)
                #pragma unroll
                for (int j = 0; j < 4; ++j) {
                    const int row = m * 16 + ((lane >> 4) << 2) + j;
                    const int key = n * 16 + (lane & 15);
                    union { bf16 b; short s; } u;
                    u.b = __float2bfloat16(sa[m][n][j]);
                    lPw[(row << 6) + key] = u.s;
                }
        __syncthreads();

        // ---- PV: ctx += P * V  (A from lPw, B from lVt, linear) ----
        short8 pf[2][2], vf[4][2];
        #pragma unroll
        for (int m = 0; m < 2; ++m)
            #pragma unroll
            for (int kk = 0; kk < 2; ++kk) {
                const int row = m * 16 + (lane & 15);
                pf[m][kk] = *(const short8*)((bf16*)lPw + row * 64 + kk * 32 + (lane >> 4) * 8);
            }
        #pragma unroll
        for (int n2 = 0; n2 < 4; ++n2)
            #pragma unroll
            for (int kk = 0; kk < 2; ++kk) {
                const int dim = n2 * 16 + (lane & 15);
                vf[n2][kk] = *(const short8*)(lVt + dim * 64 + kk * 32 + (lane >> 4) * 8);
            }
        #pragma unroll
        for (int m = 0; m < 2; ++m)
            #pragma unroll
            for (int n2 = 0; n2 < 4; ++n2)
                #pragma unroll
                for (int kk = 0; kk < 2; ++kk)
                    o[m][n2] = __builtin_amdgcn_mfma_f32_16x16x32_bf16(pf[m][kk], vf[n2][kk], o[m][n2], 0, 0, 0);

        __syncthreads();   // protect lK/lV/lVt/lP before next iteration
    }

    // ---- write ctx: row r = s*4 + b, col = h*64 + dim ----
    const int b = bh >> 4;
    const int h = bh & 15;
    #pragma unroll
    for (int m = 0; m < 2; ++m)
        #pragma unroll
        for (int n2 = 0; n2 < 4; ++n2) {
            const int dim = (h << 6) + n2 * 16 + (lane & 15);
            #pragma unroll
            for (int j = 0; j < 4; ++j) {
                const int srow = q0 + m * 16 + ((lane >> 4) << 2) + j;
                const float inv = 1.f / lrun[m][j];
                Ctx[(((srow << 2) + b) << 10) + dim] = __float2bfloat16(o[m][n2][j] * inv);
            }
        }
}

// ---------------------------------------------------------------------------
extern "C" void kernel_launch(void* const* d_in, const int* in_sizes, int n_in,
                              void* d_out, int out_size, void* d_ws, size_t ws_size,
                              hipStream_t stream)
{
    // Inputs are float32 (reference dtypes); output is float32 as well.
    const float* query = (const float*)d_in[0];   // (2048, 4, 1024)
    const float* wIn   = (const float*)d_in[1];   // (3072, 1024)
    const float* bIn   = (const float*)d_in[2];   // (3072,)
    const float* wOut  = (const float*)d_in[3];   // (1024, 1024)
    const float* bOut  = (const float*)d_in[4];   // (1024,)

    const size_t HEADSZ = (size_t)64 * 2048 * 64;   // per Q/K/V buffer (elements)
    bf16* Qws = (bf16*)d_ws;
    bf16* Kws = Qws + HEADSZ;
    bf16* Vws = Kws + HEADSZ;
    bf16* Ctx = Vws + HEADSZ;
    if (ws_size < 4 * HEADSZ * sizeof(bf16)) return;  // need 64 MB scratch

    // QKV projection: M=8192 (r=s*4+b), N=3072 (f), K=1024; A,B f32
    gemm_bt<0, 1, 1><<<dim3(24, 64), 256, 0, stream>>>(query, wIn, bIn,
                                                       Qws, Kws, Vws, 1024, 3072);
    // attention: 16 q-blocks x 64 heads (bf16 workspaces)
    attn_kernel<<<dim3(16, 64), 256, 0, stream>>>(Qws, Kws, Vws, Ctx);
    // out projection: M=8192, N=1024, K=1024; A bf16 (Ctx), B f32; f32 output
    gemm_bt<1, 0, 1><<<dim3(8, 64), 256, 0, stream>>>(Ctx, wOut, bOut,
                                                      d_out, nullptr, nullptr, 1024, 1024);
}

// Round 6
// 384.303 us; speedup vs baseline: 1.2086x; 1.2086x over previous
//
#include <hip/hip_runtime.h>
#include <hip/hip_bf16.h>

typedef __hip_bfloat16 bf16;
typedef __attribute__((ext_vector_type(8))) short short8;
typedef __attribute__((ext_vector_type(4))) float floatx4;

#define GLD_LDS(g, l) __builtin_amdgcn_global_load_lds( \
    (const __attribute__((address_space(1))) void*)(g), \
    (__attribute__((address_space(3))) void*)(l), 16, 0, 0)

// Stage a [128][32] bf16 tile into LDS from an f32 row-major source.
__device__ __forceinline__ void stage_f32(const float* __restrict__ src, int ld,
                                          bf16* lds, int t)
{
    const int sr = t >> 1;
    const int sc = (t & 1) * 16;
    const float* g = src + (long)sr * ld + sc;
    floatx4 f[4];
    #pragma unroll
    for (int i = 0; i < 4; ++i) f[i] = *(const floatx4*)(g + i * 4);
    short8 h[2];
    #pragma unroll
    for (int v = 0; v < 2; ++v)
        #pragma unroll
        for (int e = 0; e < 8; ++e) {
            union { bf16 b; short s; } u;
            u.b = __float2bfloat16(f[v * 2 + (e >> 2)][e & 3]);
            h[v][e] = u.s;
        }
    *(short8*)(lds + sr * 32 + sc)     = h[0];
    *(short8*)(lds + sr * 32 + sc + 8) = h[1];
}

// ---------------------------------------------------------------------------
// GEMM: C = A(MxK,row) * B^T (B is NxK row-major) + bias[col]
// 128x128 tile, BK=32, 4 waves (2x2 of 64x64), 16x16x32 bf16 MFMA.
// EPI=0: QKV scatter epilogue; V is stored TRANSPOSED: Vt[bh][d][s]
// EPI=1: f32 store to ((float*)o0)[r*N+col]  (d_out is f32)
// ---------------------------------------------------------------------------
template<int EPI, int AF32, int BF32>
__global__ __launch_bounds__(256, 2)
void gemm_bt(const void* __restrict__ Ap, const void* __restrict__ Bp,
             const float* __restrict__ bias,
             void* __restrict__ o0, bf16* __restrict__ o1, bf16* __restrict__ o2,
             int K, int N)
{
    __shared__ __align__(16) bf16 lA[128 * 32];
    __shared__ __align__(16) bf16 lB[128 * 32];

    const int t    = threadIdx.x;
    const int lane = t & 63;
    const int w    = t >> 6;
    const int mBase = blockIdx.y * 128;
    const int nBase = blockIdx.x * 128;
    const int wr = (w >> 1) * 64;
    const int wc = (w & 1) * 64;

    const int rowL = t >> 2;            // 0..63 (+64)
    const int colL = (t & 3) * 8;
    const bf16* gA0 = (const bf16*)Ap + (long)(mBase + rowL) * K + colL;
    const bf16* gA1 = (const bf16*)Ap + (long)(mBase + rowL + 64) * K + colL;
    const bf16* gB0 = (const bf16*)Bp + (long)(nBase + rowL) * K + colL;
    const bf16* gB1 = (const bf16*)Bp + (long)(nBase + rowL + 64) * K + colL;
    char* lAb = (char*)lA + w * 1024;
    char* lBb = (char*)lB + w * 1024;

    floatx4 acc[4][4] = {};

    for (int k0 = 0; k0 < K; k0 += 32) {
        if constexpr (AF32) {
            stage_f32((const float*)Ap + (long)mBase * K + k0, K, lA, t);
        } else {
            GLD_LDS(gA0 + k0, lAb);
            GLD_LDS(gA1 + k0, lAb + 4096);
        }
        if constexpr (BF32) {
            stage_f32((const float*)Bp + (long)nBase * K + k0, K, lB, t);
        } else {
            GLD_LDS(gB0 + k0, lBb);
            GLD_LDS(gB1 + k0, lBb + 4096);
        }
        asm volatile("s_waitcnt vmcnt(0)" ::: "memory");
        __syncthreads();

        short8 af[4], bfr[4];
        #pragma unroll
        for (int m = 0; m < 4; ++m)
            af[m] = *(const short8*)(lA + (wr + m * 16 + (lane & 15)) * 32 + (lane >> 4) * 8);
        #pragma unroll
        for (int n = 0; n < 4; ++n)
            bfr[n] = *(const short8*)(lB + (wc + n * 16 + (lane & 15)) * 32 + (lane >> 4) * 8);
        #pragma unroll
        for (int m = 0; m < 4; ++m)
            #pragma unroll
            for (int n = 0; n < 4; ++n)
                acc[m][n] = __builtin_amdgcn_mfma_f32_16x16x32_bf16(af[m], bfr[n], acc[m][n], 0, 0, 0);
        __syncthreads();
    }

    // epilogue: C frag (m,n): row = (lane>>4)*4+j, col = lane&15
    #pragma unroll
    for (int m = 0; m < 4; ++m) {
        #pragma unroll
        for (int n = 0; n < 4; ++n) {
            const int col = nBase + wc + n * 16 + (lane & 15);
            const int r0  = mBase + wr + m * 16 + ((lane >> 4) << 2);
            const float bv = bias[col];
            if constexpr (EPI == 0) {
                const int h   = col / 192;
                const int rem = col % 192;
                const int qkv = rem >> 6;
                const int d   = rem & 63;
                #pragma unroll
                for (int j = 0; j < 4; ++j) {
                    const int r = r0 + j;
                    const int s = r >> 2;      // B=4
                    const int b = r & 3;
                    const bf16 val = __float2bfloat16(acc[m][n][j] + bv);
                    if (qkv == 0)
                        ((bf16*)o0)[(((((b << 4) + h) << 11) + s) << 6) + d] = val;
                    else if (qkv == 1)
                        o1[(((((b << 4) + h) << 11) + s) << 6) + d] = val;
                    else  // V transposed: Vt[bh][d][s]
                        o2[((((b << 4) + h) << 17)) + (d << 11) + s] = val;
                }
            } else {
                #pragma unroll
                for (int j = 0; j < 4; ++j)
                    ((float*)o0)[(long)(r0 + j) * N + col] = acc[m][n][j] + bv;
            }
        }
    }
}

// ---------------------------------------------------------------------------
// Flash attention, per (head, q-block of 128). 4 waves x 32 q-rows each.
// KVBLK=64, 2 barriers/tile. V^T comes pre-transposed from the QKV GEMM.
// All LDS XOR-swizzled (byte ^= ((row&7)<<4)) on BOTH write and read ->
// fragment reads and staging writes are bank-conflict-free.
// T14 prefetch: next tile's K/Vt global loads issued under QK^T+softmax.
// ---------------------------------------------------------------------------
__global__ __launch_bounds__(256, 2)
void attn_kernel(const bf16* __restrict__ Q, const bf16* __restrict__ Kg,
                 const bf16* __restrict__ Vt, bf16* __restrict__ Ctx)
{
    __shared__ __align__(16) bf16 lK[64 * 64];     // [key][d]  swizzled
    __shared__ __align__(16) bf16 lV[64 * 64];     // [d][key]  swizzled
    __shared__ __align__(16) bf16 lP[4][32 * 64];  // per-wave [row][key] swizzled

    const int t    = threadIdx.x;
    const int lane = t & 63;
    const int w    = t >> 6;
    const int f    = lane & 15;
    const int g    = lane >> 4;
    const int bh   = blockIdx.y;                 // b*16 + h
    const int q0   = blockIdx.x * 128 + w * 32;
    const long hb  = (long)bh * 2048 * 64;
    const bf16* Qh = Q  + hb;
    const bf16* Kh = Kg + hb;
    const bf16* Vh = Vt + hb;                    // [d][s], row stride 2048

    // staging: thread covers rows srow, srow+32; 16B at col scol
    const int srow = t >> 3;                     // 0..31
    const int scol = (t & 7) * 8;                // element col (0..56)
    const int wb0 = ((srow)      * 128 + scol * 2) ^ (((srow)      & 7) << 4);
    const int wb1 = ((srow + 32) * 128 + scol * 2) ^ (((srow + 32) & 7) << 4);

    // Q fragments: rows q0 + m*16 + f, d = kk*32 + g*8
    short8 qf[2][2];
    #pragma unroll
    for (int m = 0; m < 2; ++m)
        #pragma unroll
        for (int kk = 0; kk < 2; ++kk)
            qf[m][kk] = *(const short8*)(Qh + (q0 + m * 16 + f) * 64 + kk * 32 + g * 8);

    floatx4 o[2][4] = {};
    float mrun[2][4], lrun[2][4];
    #pragma unroll
    for (int m = 0; m < 2; ++m)
        #pragma unroll
        for (int j = 0; j < 4; ++j) { mrun[m][j] = -1e30f; lrun[m][j] = 0.f; }

    const float cs = 0.125f * 1.44269504089f;    // scale * log2(e)
    char* lPw = (char*)lP[w];

    // prefetch tile 0
    short8 kR0 = *(const short8*)(Kh + (long)srow * 64 + scol);
    short8 kR1 = *(const short8*)(Kh + (long)(srow + 32) * 64 + scol);
    short8 vR0 = *(const short8*)(Vh + (long)srow * 2048 + scol);
    short8 vR1 = *(const short8*)(Vh + (long)(srow + 32) * 2048 + scol);

    for (int t0 = 0; t0 < 2048; t0 += 64) {
        // ---- staged regs -> LDS (swizzled writes, conflict-free) ----
        *(short8*)((char*)lK + wb0) = kR0;
        *(short8*)((char*)lK + wb1) = kR1;
        *(short8*)((char*)lV + wb0) = vR0;
        *(short8*)((char*)lV + wb1) = vR1;
        __syncthreads();

        // ---- K fragment reads (swizzled, conflict-free) ----
        short8 kf[4][2];
        #pragma unroll
        for (int n = 0; n < 4; ++n)
            #pragma unroll
            for (int kk = 0; kk < 2; ++kk) {
                const int key = n * 16 + f;
                const int byte = (key * 128 + kk * 64 + g * 16) ^ ((key & 7) << 4);
                kf[n][kk] = *(const short8*)((char*)lK + byte);
            }

        // ---- T14: issue next tile's global loads under compute ----
        if (t0 + 64 < 2048) {
            kR0 = *(const short8*)(Kh + (long)(t0 + 64 + srow) * 64 + scol);
            kR1 = *(const short8*)(Kh + (long)(t0 + 64 + srow + 32) * 64 + scol);
            vR0 = *(const short8*)(Vh + (long)srow * 2048 + t0 + 64 + scol);
            vR1 = *(const short8*)(Vh + (long)(srow + 32) * 2048 + t0 + 64 + scol);
        }

        // ---- QK^T ----
        floatx4 sa[2][4] = {};
        #pragma unroll
        for (int m = 0; m < 2; ++m)
            #pragma unroll
            for (int n = 0; n < 4; ++n)
                #pragma unroll
                for (int kk = 0; kk < 2; ++kk)
                    sa[m][n] = __builtin_amdgcn_mfma_f32_16x16x32_bf16(qf[m][kk], kf[n][kk], sa[m][n], 0, 0, 0);

        // ---- V^T fragment reads (swizzled, conflict-free) ----
        short8 vf[4][2];
        #pragma unroll
        for (int n2 = 0; n2 < 4; ++n2)
            #pragma unroll
            for (int kk = 0; kk < 2; ++kk) {
                const int dim = n2 * 16 + f;
                const int byte = (dim * 128 + kk * 64 + g * 16) ^ ((dim & 7) << 4);
                vf[n2][kk] = *(const short8*)((char*)lV + byte);
            }

        // ---- online softmax (rows m*16 + g*4 + j, over 64 keys) ----
        #pragma unroll
        for (int m = 0; m < 2; ++m)
            #pragma unroll
            for (int n = 0; n < 4; ++n)
                sa[m][n] *= cs;
        #pragma unroll
        for (int m = 0; m < 2; ++m)
            #pragma unroll
            for (int j = 0; j < 4; ++j) {
                float mx = fmaxf(fmaxf(sa[m][0][j], sa[m][1][j]),
                                 fmaxf(sa[m][2][j], sa[m][3][j]));
                mx = fmaxf(mx, __shfl_xor(mx, 1));
                mx = fmaxf(mx, __shfl_xor(mx, 2));
                mx = fmaxf(mx, __shfl_xor(mx, 4));
                mx = fmaxf(mx, __shfl_xor(mx, 8));
                const float mnew = fmaxf(mrun[m][j], mx);
                const float fac  = exp2f(mrun[m][j] - mnew);
                mrun[m][j] = mnew;
                float rs = 0.f;
                #pragma unroll
                for (int n = 0; n < 4; ++n) {
                    const float p = exp2f(sa[m][n][j] - mnew);
                    sa[m][n][j] = p;
                    rs += p;
                }
                rs += __shfl_xor(rs, 1);
                rs += __shfl_xor(rs, 2);
                rs += __shfl_xor(rs, 4);
                rs += __shfl_xor(rs, 8);
                lrun[m][j] = lrun[m][j] * fac + rs;
                #pragma unroll
                for (int n2 = 0; n2 < 4; ++n2)
                    o[m][n2][j] *= fac;
            }

        // ---- P -> per-wave swizzled LDS (C-layout scatter) ----
        #pragma unroll
        for (int m = 0; m < 2; ++m)
            #pragma unroll
            for (int n = 0; n < 4; ++n)
                #pragma unroll
                for (int j = 0; j < 4; ++j) {
                    const int row = m * 16 + (g << 2) + j;
                    const int key = n * 16 + f;
                    const int byte = (row * 128 + key * 2) ^ ((row & 7) << 4);
                    union { bf16 b; short s; } u;
                    u.b = __float2bfloat16(sa[m][n][j]);
                    *(short*)(lPw + byte) = u.s;
                }
        asm volatile("s_waitcnt lgkmcnt(0)" ::: "memory");
        __builtin_amdgcn_sched_barrier(0);

        // ---- PV: A from lPw (swizzled), B from lV ----
        short8 pf[2][2];
        #pragma unroll
        for (int m = 0; m < 2; ++m)
            #pragma unroll
            for (int kk = 0; kk < 2; ++kk) {
                const int row = m * 16 + f;
                const int byte = (row * 128 + kk * 64 + g * 16) ^ ((row & 7) << 4);
                pf[m][kk] = *(const short8*)(lPw + byte);
            }
        #pragma unroll
        for (int m = 0; m < 2; ++m)
            #pragma unroll
            for (int n2 = 0; n2 < 4; ++n2)
                #pragma unroll
                for (int kk = 0; kk < 2; ++kk)
                    o[m][n2] = __builtin_amdgcn_mfma_f32_16x16x32_bf16(pf[m][kk], vf[n2][kk], o[m][n2], 0, 0, 0);

        __syncthreads();   // all LDS reads done before next tile's writes
    }

    // ---- write ctx: row r = s*4 + b, col = h*64 + dim ----
    const int b = bh >> 4;
    const int h = bh & 15;
    #pragma unroll
    for (int m = 0; m < 2; ++m)
        #pragma unroll
        for (int n2 = 0; n2 < 4; ++n2) {
            const int dim = (h << 6) + n2 * 16 + f;
            #pragma unroll
            for (int j = 0; j < 4; ++j) {
                const int srw = q0 + m * 16 + (g << 2) + j;
                const float inv = 1.f / lrun[m][j];
                Ctx[(((srw << 2) + b) << 10) + dim] = __float2bfloat16(o[m][n2][j] * inv);
            }
        }
}

// ---------------------------------------------------------------------------
extern "C" void kernel_launch(void* const* d_in, const int* in_sizes, int n_in,
                              void* d_out, int out_size, void* d_ws, size_t ws_size,
                              hipStream_t stream)
{
    const float* query = (const float*)d_in[0];   // (2048, 4, 1024) f32
    const float* wIn   = (const float*)d_in[1];   // (3072, 1024) f32
    const float* bIn   = (const float*)d_in[2];   // (3072,) f32
    const float* wOut  = (const float*)d_in[3];   // (1024, 1024) f32
    const float* bOut  = (const float*)d_in[4];   // (1024,) f32

    const size_t HEADSZ = (size_t)64 * 2048 * 64;
    bf16* Qws = (bf16*)d_ws;
    bf16* Kws = Qws + HEADSZ;
    bf16* Vtw = Kws + HEADSZ;     // TRANSPOSED: [bh][d][s]
    bf16* Ctx = Vtw + HEADSZ;
    if (ws_size < 4 * HEADSZ * sizeof(bf16)) return;

    // QKV projection: M=8192 (r=s*4+b), N=3072, K=1024; A,B f32
    gemm_bt<0, 1, 1><<<dim3(24, 64), 256, 0, stream>>>(query, wIn, bIn,
                                                       Qws, Kws, Vtw, 1024, 3072);
    // attention: 16 q-blocks x 64 heads
    attn_kernel<<<dim3(16, 64), 256, 0, stream>>>(Qws, Kws, Vtw, Ctx);
    // out projection: M=8192, N=1024, K=1024; A bf16 (Ctx), B f32; f32 out
    gemm_bt<1, 0, 1><<<dim3(8, 64), 256, 0, stream>>>(Ctx, wOut, bOut,
                                                      d_out, nullptr, nullptr, 1024, 1024);
}

// Round 7
// 291.973 us; speedup vs baseline: 1.5908x; 1.3162x over previous
//
#include <hip/hip_runtime.h>
#include <hip/hip_bf16.h>

typedef __hip_bfloat16 bf16;
typedef __attribute__((ext_vector_type(8))) short short8;
typedef __attribute__((ext_vector_type(4))) float floatx4;

#define GLD_LDS(g, l) __builtin_amdgcn_global_load_lds( \
    (const __attribute__((address_space(1))) void*)(g), \
    (__attribute__((address_space(3))) void*)(l), 16, 0, 0)

// Stage a [128][32] bf16 tile into LDS from an f32 row-major source.
__device__ __forceinline__ void stage_f32(const float* __restrict__ src, int ld,
                                          bf16* lds, int t)
{
    const int sr = t >> 1;
    const int sc = (t & 1) * 16;
    const float* g = src + (long)sr * ld + sc;
    floatx4 f[4];
    #pragma unroll
    for (int i = 0; i < 4; ++i) f[i] = *(const floatx4*)(g + i * 4);
    short8 h[2];
    #pragma unroll
    for (int v = 0; v < 2; ++v)
        #pragma unroll
        for (int e = 0; e < 8; ++e) {
            union { bf16 b; short s; } u;
            u.b = __float2bfloat16(f[v * 2 + (e >> 2)][e & 3]);
            h[v][e] = u.s;
        }
    *(short8*)(lds + sr * 32 + sc)     = h[0];
    *(short8*)(lds + sr * 32 + sc + 8) = h[1];
}

// ---------------------------------------------------------------------------
// GEMM: C = A(MxK,row) * B^T (B is NxK row-major) + bias[col]
// 128x128 tile, BK=32, 4 waves (2x2 of 64x64), 16x16x32 bf16 MFMA.
// EPI=0: QKV scatter epilogue; V stored TRANSPOSED: Vt[bh][d][s]
// EPI=1: f32 store to ((float*)o0)[r*N+col]
// ---------------------------------------------------------------------------
template<int EPI, int AF32, int BF32>
__global__ __launch_bounds__(256, 2)
void gemm_bt(const void* __restrict__ Ap, const void* __restrict__ Bp,
             const float* __restrict__ bias,
             void* __restrict__ o0, bf16* __restrict__ o1, bf16* __restrict__ o2,
             int K, int N)
{
    __shared__ __align__(16) bf16 lA[128 * 32];
    __shared__ __align__(16) bf16 lB[128 * 32];

    const int t    = threadIdx.x;
    const int lane = t & 63;
    const int w    = t >> 6;
    const int mBase = blockIdx.y * 128;
    const int nBase = blockIdx.x * 128;
    const int wr = (w >> 1) * 64;
    const int wc = (w & 1) * 64;

    const int rowL = t >> 2;
    const int colL = (t & 3) * 8;
    const bf16* gA0 = (const bf16*)Ap + (long)(mBase + rowL) * K + colL;
    const bf16* gA1 = (const bf16*)Ap + (long)(mBase + rowL + 64) * K + colL;
    const bf16* gB0 = (const bf16*)Bp + (long)(nBase + rowL) * K + colL;
    const bf16* gB1 = (const bf16*)Bp + (long)(nBase + rowL + 64) * K + colL;
    char* lAb = (char*)lA + w * 1024;
    char* lBb = (char*)lB + w * 1024;

    floatx4 acc[4][4] = {};

    for (int k0 = 0; k0 < K; k0 += 32) {
        if constexpr (AF32) {
            stage_f32((const float*)Ap + (long)mBase * K + k0, K, lA, t);
        } else {
            GLD_LDS(gA0 + k0, lAb);
            GLD_LDS(gA1 + k0, lAb + 4096);
        }
        if constexpr (BF32) {
            stage_f32((const float*)Bp + (long)nBase * K + k0, K, lB, t);
        } else {
            GLD_LDS(gB0 + k0, lBb);
            GLD_LDS(gB1 + k0, lBb + 4096);
        }
        asm volatile("s_waitcnt vmcnt(0)" ::: "memory");
        __syncthreads();

        short8 af[4], bfr[4];
        #pragma unroll
        for (int m = 0; m < 4; ++m)
            af[m] = *(const short8*)(lA + (wr + m * 16 + (lane & 15)) * 32 + (lane >> 4) * 8);
        #pragma unroll
        for (int n = 0; n < 4; ++n)
            bfr[n] = *(const short8*)(lB + (wc + n * 16 + (lane & 15)) * 32 + (lane >> 4) * 8);
        #pragma unroll
        for (int m = 0; m < 4; ++m)
            #pragma unroll
            for (int n = 0; n < 4; ++n)
                acc[m][n] = __builtin_amdgcn_mfma_f32_16x16x32_bf16(af[m], bfr[n], acc[m][n], 0, 0, 0);
        __syncthreads();
    }

    #pragma unroll
    for (int m = 0; m < 4; ++m) {
        #pragma unroll
        for (int n = 0; n < 4; ++n) {
            const int col = nBase + wc + n * 16 + (lane & 15);
            const int r0  = mBase + wr + m * 16 + ((lane >> 4) << 2);
            const float bv = bias[col];
            if constexpr (EPI == 0) {
                const int h   = col / 192;
                const int rem = col % 192;
                const int qkv = rem >> 6;
                const int d   = rem & 63;
                #pragma unroll
                for (int j = 0; j < 4; ++j) {
                    const int r = r0 + j;
                    const int s = r >> 2;
                    const int b = r & 3;
                    const bf16 val = __float2bfloat16(acc[m][n][j] + bv);
                    if (qkv == 0)
                        ((bf16*)o0)[(((((b << 4) + h) << 11) + s) << 6) + d] = val;
                    else if (qkv == 1)
                        o1[(((((b << 4) + h) << 11) + s) << 6) + d] = val;
                    else  // V transposed: Vt[bh][d][s]
                        o2[((((b << 4) + h) << 17)) + (d << 11) + s] = val;
                }
            } else {
                #pragma unroll
                for (int j = 0; j < 4; ++j)
                    ((float*)o0)[(long)(r0 + j) * N + col] = acc[m][n][j] + bv;
            }
        }
    }
}

// ---------------------------------------------------------------------------
// Flash attention, swapped-QK^T structure: mfma(K,Q) -> S^T[key][q], so each
// lane holds a full 16-value key-slice for ONE q (q = m*16 + (lane&15)).
// K is staged with sigma-permuted tile rows (sigma = bit-perm [b5 b3 b2 b4 b1 b0])
// which makes the PV A-fragment IN-LANE (sigma∘tau = id): no P LDS round-trip.
// Softmax: in-lane reduce + 2 shfl_xor (16/32). lP eliminated; LDS = 16 KB.
// ---------------------------------------------------------------------------
__global__ __launch_bounds__(256, 2)
void attn_kernel(const bf16* __restrict__ Q, const bf16* __restrict__ Kg,
                 const bf16* __restrict__ Vt, bf16* __restrict__ Ctx)
{
    __shared__ __align__(16) bf16 lK[64 * 64];   // row c = K[t0+sigma(c)], swizzled
    __shared__ __align__(16) bf16 lV[64 * 64];   // [d][key-physical], swizzled

    const int t    = threadIdx.x;
    const int lane = t & 63;
    const int w    = t >> 6;
    const int f    = lane & 15;
    const int g    = lane >> 4;
    const int bh   = blockIdx.y;
    const int q0   = blockIdx.x * 128 + w * 32;
    const long hb  = (long)bh * 2048 * 64;
    const bf16* Qh = Q  + hb;
    const bf16* Kh = Kg + hb;
    const bf16* Vh = Vt + hb;                    // [d][s], row stride 2048

    // staging: thread covers LDS rows srow, srow+32; 16B at col scol
    const int srow = t >> 3;                     // 0..31
    const int scol = (t & 7) * 8;
    // sigma(srow): bits [b4 b3 b2] -> [b3 b2 b4]
    const int sig0 = (srow & 3) | ((srow & 16) >> 2) | ((srow & 12) << 1);
    const int wb0 = ((srow)      * 128 + scol * 2) ^ (((srow)      & 7) << 4);
    const int wb1 = ((srow + 32) * 128 + scol * 2) ^ (((srow + 32) & 7) << 4);

    // Q fragments: rows q0 + m*16 + f, d = kk*32 + g*8
    short8 qf[2][2];
    #pragma unroll
    for (int m = 0; m < 2; ++m)
        #pragma unroll
        for (int kk = 0; kk < 2; ++kk)
            qf[m][kk] = *(const short8*)(Qh + (q0 + m * 16 + f) * 64 + kk * 32 + g * 8);

    floatx4 o[2][4] = {};
    float mrun[2] = {-1e30f, -1e30f};
    float lrun[2] = {0.f, 0.f};

    const float cs = 0.125f * 1.44269504089f;    // scale * log2(e)
    const int srcBase = g * 20;                  // lane with f' = g*4+j (j added)

    // prefetch tile 0 (K rows sigma-permuted)
    short8 kR0 = *(const short8*)(Kh + (long)sig0 * 64 + scol);
    short8 kR1 = *(const short8*)(Kh + (long)(sig0 + 32) * 64 + scol);
    short8 vR0 = *(const short8*)(Vh + (long)srow * 2048 + scol);
    short8 vR1 = *(const short8*)(Vh + (long)(srow + 32) * 2048 + scol);

    for (int t0 = 0; t0 < 2048; t0 += 64) {
        // ---- staged regs -> LDS (swizzled, conflict-free) ----
        *(short8*)((char*)lK + wb0) = kR0;
        *(short8*)((char*)lK + wb1) = kR1;
        *(short8*)((char*)lV + wb0) = vR0;
        *(short8*)((char*)lV + wb1) = vR1;
        __syncthreads();

        // ---- K fragments (rows = sigma-labels n*16+f) ----
        short8 kf[4][2];
        #pragma unroll
        for (int n = 0; n < 4; ++n)
            #pragma unroll
            for (int kk = 0; kk < 2; ++kk) {
                const int key = n * 16 + f;
                const int byte = (key * 128 + kk * 64 + g * 16) ^ ((key & 7) << 4);
                kf[n][kk] = *(const short8*)((char*)lK + byte);
            }

        // ---- T14: next tile's global loads issued under compute ----
        if (t0 + 64 < 2048) {
            kR0 = *(const short8*)(Kh + (long)(t0 + 64 + sig0) * 64 + scol);
            kR1 = *(const short8*)(Kh + (long)(t0 + 64 + sig0 + 32) * 64 + scol);
            vR0 = *(const short8*)(Vh + (long)srow * 2048 + t0 + 64 + scol);
            vR1 = *(const short8*)(Vh + (long)(srow + 32) * 2048 + t0 + 64 + scol);
        }

        // ---- swapped QK^T: sa2[n][m] = S^T[key][q] ----
        floatx4 sa2[4][2] = {};
        #pragma unroll
        for (int n = 0; n < 4; ++n)
            #pragma unroll
            for (int m = 0; m < 2; ++m)
                #pragma unroll
                for (int kk = 0; kk < 2; ++kk)
                    sa2[n][m] = __builtin_amdgcn_mfma_f32_16x16x32_bf16(kf[n][kk], qf[m][kk], sa2[n][m], 0, 0, 0);

        // ---- V^T fragments (physical key order) ----
        short8 vf[4][2];
        #pragma unroll
        for (int n2 = 0; n2 < 4; ++n2)
            #pragma unroll
            for (int kk = 0; kk < 2; ++kk) {
                const int dim = n2 * 16 + f;
                const int byte = (dim * 128 + kk * 64 + g * 16) ^ ((dim & 7) << 4);
                vf[n2][kk] = *(const short8*)((char*)lV + byte);
            }

        // ---- online softmax: lane-local over 16 keys + 2 shfl_xor ----
        float fac[2];
        #pragma unroll
        for (int m = 0; m < 2; ++m) {
            float mx = -1e30f;
            #pragma unroll
            for (int n = 0; n < 4; ++n)
                #pragma unroll
                for (int j = 0; j < 4; ++j) {
                    sa2[n][m][j] *= cs;
                    mx = fmaxf(mx, sa2[n][m][j]);
                }
            mx = fmaxf(mx, __shfl_xor(mx, 16));
            mx = fmaxf(mx, __shfl_xor(mx, 32));
            const float mnew = fmaxf(mrun[m], mx);
            fac[m] = exp2f(mrun[m] - mnew);
            mrun[m] = mnew;
            float rs = 0.f;
            #pragma unroll
            for (int n = 0; n < 4; ++n)
                #pragma unroll
                for (int j = 0; j < 4; ++j) {
                    const float p = exp2f(sa2[n][m][j] - mnew);
                    sa2[n][m][j] = p;
                    rs += p;
                }
            rs += __shfl_xor(rs, 16);
            rs += __shfl_xor(rs, 32);
            lrun[m] = lrun[m] * fac[m] + rs;
        }

        // ---- rescale o (fac redistributed into (g,j) lane-space) ----
        #pragma unroll
        for (int m = 0; m < 2; ++m) {
            const float f0 = __shfl(fac[m], srcBase + 0);
            const float f1 = __shfl(fac[m], srcBase + 1);
            const float f2 = __shfl(fac[m], srcBase + 2);
            const float f3 = __shfl(fac[m], srcBase + 3);
            #pragma unroll
            for (int n2 = 0; n2 < 4; ++n2) {
                o[m][n2][0] *= f0; o[m][n2][1] *= f1;
                o[m][n2][2] *= f2; o[m][n2][3] *= f3;
            }
        }

        // ---- P -> A-fragment, fully in-lane (sigma∘tau = id) ----
        short8 pf[2][2];
        #pragma unroll
        for (int m = 0; m < 2; ++m)
            #pragma unroll
            for (int kk = 0; kk < 2; ++kk)
                #pragma unroll
                for (int e = 0; e < 8; ++e) {
                    union { bf16 b; short s; } u;
                    u.b = __float2bfloat16(sa2[2 * kk + (e >> 2)][m][e & 3]);
                    pf[m][kk][e] = u.s;
                }

        // ---- PV ----
        #pragma unroll
        for (int m = 0; m < 2; ++m)
            #pragma unroll
            for (int n2 = 0; n2 < 4; ++n2)
                #pragma unroll
                for (int kk = 0; kk < 2; ++kk)
                    o[m][n2] = __builtin_amdgcn_mfma_f32_16x16x32_bf16(pf[m][kk], vf[n2][kk], o[m][n2], 0, 0, 0);

        __syncthreads();
    }

    // ---- write ctx: inv = 1/lrun at q-row = m*16+g*4+j ----
    const int b = bh >> 4;
    const int h = bh & 15;
    #pragma unroll
    for (int m = 0; m < 2; ++m) {
        float inv[4];
        #pragma unroll
        for (int j = 0; j < 4; ++j)
            inv[j] = 1.f / __shfl(lrun[m], srcBase + j);
        #pragma unroll
        for (int n2 = 0; n2 < 4; ++n2) {
            const int dim = (h << 6) + n2 * 16 + f;
            #pragma unroll
            for (int j = 0; j < 4; ++j) {
                const int srw = q0 + m * 16 + (g << 2) + j;
                Ctx[(((srw << 2) + b) << 10) + dim] = __float2bfloat16(o[m][n2][j] * inv[j]);
            }
        }
    }
}

// ---------------------------------------------------------------------------
extern "C" void kernel_launch(void* const* d_in, const int* in_sizes, int n_in,
                              void* d_out, int out_size, void* d_ws, size_t ws_size,
                              hipStream_t stream)
{
    const float* query = (const float*)d_in[0];
    const float* wIn   = (const float*)d_in[1];
    const float* bIn   = (const float*)d_in[2];
    const float* wOut  = (const float*)d_in[3];
    const float* bOut  = (const float*)d_in[4];

    const size_t HEADSZ = (size_t)64 * 2048 * 64;
    bf16* Qws = (bf16*)d_ws;
    bf16* Kws = Qws + HEADSZ;
    bf16* Vtw = Kws + HEADSZ;     // TRANSPOSED: [bh][d][s]
    bf16* Ctx = Vtw + HEADSZ;
    if (ws_size < 4 * HEADSZ * sizeof(bf16)) return;

    gemm_bt<0, 1, 1><<<dim3(24, 64), 256, 0, stream>>>(query, wIn, bIn,
                                                       Qws, Kws, Vtw, 1024, 3072);
    attn_kernel<<<dim3(16, 64), 256, 0, stream>>>(Qws, Kws, Vtw, Ctx);
    gemm_bt<1, 0, 1><<<dim3(8, 64), 256, 0, stream>>>(Ctx, wOut, bOut,
                                                      d_out, nullptr, nullptr, 1024, 1024);
}

// Round 8
// 271.860 us; speedup vs baseline: 1.7085x; 1.0740x over previous
//
#include <hip/hip_runtime.h>
#include <hip/hip_bf16.h>

typedef __hip_bfloat16 bf16;
typedef __attribute__((ext_vector_type(8))) short short8;
typedef __attribute__((ext_vector_type(4))) float floatx4;

#define GLD_LDS(g, l) __builtin_amdgcn_global_load_lds( \
    (const __attribute__((address_space(1))) void*)(g), \
    (__attribute__((address_space(3))) void*)(l), 16, 0, 0)

#define CS 0.18033688f   // 0.125 * log2(e), folded into Q at QKV epilogue

// f32 -> bf16 bulk convert, 8 elem/thread
__global__ __launch_bounds__(256)
void cvt_kernel(const float* __restrict__ in, bf16* __restrict__ out, int n8)
{
    const int i = blockIdx.x * 256 + threadIdx.x;
    if (i >= n8) return;
    const float* p = in + (long)i * 8;
    floatx4 a = *(const floatx4*)p;
    floatx4 b = *(const floatx4*)(p + 4);
    short8 h;
    #pragma unroll
    for (int e = 0; e < 4; ++e) {
        union { bf16 v; short s; } u0, u1;
        u0.v = __float2bfloat16(a[e]); h[e]     = u0.s;
        u1.v = __float2bfloat16(b[e]); h[e + 4] = u1.s;
    }
    *(short8*)(out + (long)i * 8) = h;
}

// Stage a [128][32] bf16 tile into LDS from an f32 row-major source.
__device__ __forceinline__ void stage_f32(const float* __restrict__ src, int ld,
                                          bf16* lds, int t)
{
    const int sr = t >> 1;
    const int sc = (t & 1) * 16;
    const float* g = src + (long)sr * ld + sc;
    floatx4 f[4];
    #pragma unroll
    for (int i = 0; i < 4; ++i) f[i] = *(const floatx4*)(g + i * 4);
    short8 h[2];
    #pragma unroll
    for (int v = 0; v < 2; ++v)
        #pragma unroll
        for (int e = 0; e < 8; ++e) {
            union { bf16 b; short s; } u;
            u.b = __float2bfloat16(f[v * 2 + (e >> 2)][e & 3]);
            h[v][e] = u.s;
        }
    *(short8*)(lds + sr * 32 + sc)     = h[0];
    *(short8*)(lds + sr * 32 + sc + 8) = h[1];
}

// ---------------------------------------------------------------------------
// GEMM: C = A(MxK,row) * B^T (B NxK row-major) + bias[col]
// 128x128 tile, BK=32, 4 waves, 16x16x32 bf16 MFMA.
// EPI=0: QKV scatter; Q scaled by CS; V stored transposed Vt[bh][d][s]
// EPI=1: f32 store to d_out
// ---------------------------------------------------------------------------
template<int EPI, int AF32, int BF32>
__global__ __launch_bounds__(256, 2)
void gemm_bt(const void* __restrict__ Ap, const void* __restrict__ Bp,
             const float* __restrict__ bias,
             void* __restrict__ o0, bf16* __restrict__ o1, bf16* __restrict__ o2,
             int K, int N)
{
    __shared__ __align__(16) bf16 lA[128 * 32];
    __shared__ __align__(16) bf16 lB[128 * 32];

    const int t    = threadIdx.x;
    const int lane = t & 63;
    const int w    = t >> 6;
    const int mBase = blockIdx.y * 128;
    const int nBase = blockIdx.x * 128;
    const int wr = (w >> 1) * 64;
    const int wc = (w & 1) * 64;

    const int rowL = t >> 2;
    const int colL = (t & 3) * 8;
    const bf16* gA0 = (const bf16*)Ap + (long)(mBase + rowL) * K + colL;
    const bf16* gA1 = (const bf16*)Ap + (long)(mBase + rowL + 64) * K + colL;
    const bf16* gB0 = (const bf16*)Bp + (long)(nBase + rowL) * K + colL;
    const bf16* gB1 = (const bf16*)Bp + (long)(nBase + rowL + 64) * K + colL;
    char* lAb = (char*)lA + w * 1024;
    char* lBb = (char*)lB + w * 1024;

    floatx4 acc[4][4] = {};

    for (int k0 = 0; k0 < K; k0 += 32) {
        if constexpr (AF32) {
            stage_f32((const float*)Ap + (long)mBase * K + k0, K, lA, t);
        } else {
            GLD_LDS(gA0 + k0, lAb);
            GLD_LDS(gA1 + k0, lAb + 4096);
        }
        if constexpr (BF32) {
            stage_f32((const float*)Bp + (long)nBase * K + k0, K, lB, t);
        } else {
            GLD_LDS(gB0 + k0, lBb);
            GLD_LDS(gB1 + k0, lBb + 4096);
        }
        asm volatile("s_waitcnt vmcnt(0)" ::: "memory");
        __syncthreads();

        short8 af[4], bfr[4];
        #pragma unroll
        for (int m = 0; m < 4; ++m)
            af[m] = *(const short8*)(lA + (wr + m * 16 + (lane & 15)) * 32 + (lane >> 4) * 8);
        #pragma unroll
        for (int n = 0; n < 4; ++n)
            bfr[n] = *(const short8*)(lB + (wc + n * 16 + (lane & 15)) * 32 + (lane >> 4) * 8);
        #pragma unroll
        for (int m = 0; m < 4; ++m)
            #pragma unroll
            for (int n = 0; n < 4; ++n)
                acc[m][n] = __builtin_amdgcn_mfma_f32_16x16x32_bf16(af[m], bfr[n], acc[m][n], 0, 0, 0);
        __syncthreads();
    }

    #pragma unroll
    for (int m = 0; m < 4; ++m) {
        #pragma unroll
        for (int n = 0; n < 4; ++n) {
            const int col = nBase + wc + n * 16 + (lane & 15);
            const int r0  = mBase + wr + m * 16 + ((lane >> 4) << 2);
            const float bv = bias[col];
            if constexpr (EPI == 0) {
                const int h   = col / 192;
                const int rem = col % 192;
                const int qkv = rem >> 6;
                const int d   = rem & 63;
                #pragma unroll
                for (int j = 0; j < 4; ++j) {
                    const int r = r0 + j;
                    const int s = r >> 2;
                    const int b = r & 3;
                    const float v = acc[m][n][j] + bv;
                    if (qkv == 0)   // Q pre-scaled by CS for the attn softmax
                        ((bf16*)o0)[(((((b << 4) + h) << 11) + s) << 6) + d] =
                            __float2bfloat16(v * CS);
                    else if (qkv == 1)
                        o1[(((((b << 4) + h) << 11) + s) << 6) + d] = __float2bfloat16(v);
                    else            // V transposed: Vt[bh][d][s]
                        o2[((((b << 4) + h) << 17)) + (d << 11) + s] = __float2bfloat16(v);
                }
            } else {
                #pragma unroll
                for (int j = 0; j < 4; ++j)
                    ((float*)o0)[(long)(r0 + j) * N + col] = acc[m][n][j] + bv;
            }
        }
    }
}

// ---------------------------------------------------------------------------
// Flash attention, swapped-QK^T (mfma(K,Q) -> S^T), sigma-permuted K rows so
// the PV A-fragment is in-lane. Q pre-scaled by CS. T13 defer-max (THR=8).
// T5 setprio around MFMA clusters.
// ---------------------------------------------------------------------------
__global__ __launch_bounds__(256, 2)
void attn_kernel(const bf16* __restrict__ Q, const bf16* __restrict__ Kg,
                 const bf16* __restrict__ Vt, bf16* __restrict__ Ctx)
{
    __shared__ __align__(16) bf16 lK[64 * 64];   // row c = K[t0+sigma(c)], swizzled
    __shared__ __align__(16) bf16 lV[64 * 64];   // [d][key], swizzled

    const int t    = threadIdx.x;
    const int lane = t & 63;
    const int w    = t >> 6;
    const int f    = lane & 15;
    const int g    = lane >> 4;
    const int bh   = blockIdx.y;
    const int q0   = blockIdx.x * 128 + w * 32;
    const long hb  = (long)bh * 2048 * 64;
    const bf16* Qh = Q  + hb;
    const bf16* Kh = Kg + hb;
    const bf16* Vh = Vt + hb;                    // [d][s], row stride 2048

    const int srow = t >> 3;                     // 0..31
    const int scol = (t & 7) * 8;
    const int sig0 = (srow & 3) | ((srow & 16) >> 2) | ((srow & 12) << 1);
    const int wb0 = ((srow)      * 128 + scol * 2) ^ (((srow)      & 7) << 4);
    const int wb1 = ((srow + 32) * 128 + scol * 2) ^ (((srow + 32) & 7) << 4);

    short8 qf[2][2];
    #pragma unroll
    for (int m = 0; m < 2; ++m)
        #pragma unroll
        for (int kk = 0; kk < 2; ++kk)
            qf[m][kk] = *(const short8*)(Qh + (q0 + m * 16 + f) * 64 + kk * 32 + g * 8);

    floatx4 o[2][4] = {};
    float mrun[2] = {-1e30f, -1e30f};
    float lrun[2] = {0.f, 0.f};
    const int srcBase = g * 20;

    // prefetch tile 0
    short8 kR0 = *(const short8*)(Kh + (long)sig0 * 64 + scol);
    short8 kR1 = *(const short8*)(Kh + (long)(sig0 + 32) * 64 + scol);
    short8 vR0 = *(const short8*)(Vh + (long)srow * 2048 + scol);
    short8 vR1 = *(const short8*)(Vh + (long)(srow + 32) * 2048 + scol);

    for (int t0 = 0; t0 < 2048; t0 += 64) {
        *(short8*)((char*)lK + wb0) = kR0;
        *(short8*)((char*)lK + wb1) = kR1;
        *(short8*)((char*)lV + wb0) = vR0;
        *(short8*)((char*)lV + wb1) = vR1;
        __syncthreads();

        short8 kf[4][2];
        #pragma unroll
        for (int n = 0; n < 4; ++n)
            #pragma unroll
            for (int kk = 0; kk < 2; ++kk) {
                const int key = n * 16 + f;
                const int byte = (key * 128 + kk * 64 + g * 16) ^ ((key & 7) << 4);
                kf[n][kk] = *(const short8*)((char*)lK + byte);
            }

        if (t0 + 64 < 2048) {
            kR0 = *(const short8*)(Kh + (long)(t0 + 64 + sig0) * 64 + scol);
            kR1 = *(const short8*)(Kh + (long)(t0 + 64 + sig0 + 32) * 64 + scol);
            vR0 = *(const short8*)(Vh + (long)srow * 2048 + t0 + 64 + scol);
            vR1 = *(const short8*)(Vh + (long)(srow + 32) * 2048 + t0 + 64 + scol);
        }

        // ---- swapped QK^T: sa2[n][m] = S^T[key][q] (already CS-scaled) ----
        floatx4 sa2[4][2] = {};
        __builtin_amdgcn_s_setprio(1);
        #pragma unroll
        for (int n = 0; n < 4; ++n)
            #pragma unroll
            for (int m = 0; m < 2; ++m)
                #pragma unroll
                for (int kk = 0; kk < 2; ++kk)
                    sa2[n][m] = __builtin_amdgcn_mfma_f32_16x16x32_bf16(kf[n][kk], qf[m][kk], sa2[n][m], 0, 0, 0);
        __builtin_amdgcn_s_setprio(0);

        short8 vf[4][2];
        #pragma unroll
        for (int n2 = 0; n2 < 4; ++n2)
            #pragma unroll
            for (int kk = 0; kk < 2; ++kk) {
                const int dim = n2 * 16 + f;
                const int byte = (dim * 128 + kk * 64 + g * 16) ^ ((dim & 7) << 4);
                vf[n2][kk] = *(const short8*)((char*)lV + byte);
            }

        // ---- online softmax (lane-local 16 + 2 shfl), T13 defer-max ----
        #pragma unroll
        for (int m = 0; m < 2; ++m) {
            float mx = -1e30f;
            #pragma unroll
            for (int n = 0; n < 4; ++n)
                #pragma unroll
                for (int j = 0; j < 4; ++j)
                    mx = fmaxf(mx, sa2[n][m][j]);
            mx = fmaxf(mx, __shfl_xor(mx, 16));
            mx = fmaxf(mx, __shfl_xor(mx, 32));
            if (__all(mx <= mrun[m] + 8.f)) {
                // defer: keep old max, P bounded by 2^8, no o-rescale
                float rs = 0.f;
                #pragma unroll
                for (int n = 0; n < 4; ++n)
                    #pragma unroll
                    for (int j = 0; j < 4; ++j) {
                        const float p = exp2f(sa2[n][m][j] - mrun[m]);
                        sa2[n][m][j] = p;
                        rs += p;
                    }
                rs += __shfl_xor(rs, 16);
                rs += __shfl_xor(rs, 32);
                lrun[m] += rs;
            } else {
                const float mnew = fmaxf(mrun[m], mx);
                const float fc = exp2f(mrun[m] - mnew);
                mrun[m] = mnew;
                float rs = 0.f;
                #pragma unroll
                for (int n = 0; n < 4; ++n)
                    #pragma unroll
                    for (int j = 0; j < 4; ++j) {
                        const float p = exp2f(sa2[n][m][j] - mnew);
                        sa2[n][m][j] = p;
                        rs += p;
                    }
                rs += __shfl_xor(rs, 16);
                rs += __shfl_xor(rs, 32);
                lrun[m] = lrun[m] * fc + rs;
                const float f0 = __shfl(fc, srcBase + 0);
                const float f1 = __shfl(fc, srcBase + 1);
                const float f2 = __shfl(fc, srcBase + 2);
                const float f3 = __shfl(fc, srcBase + 3);
                #pragma unroll
                for (int n2 = 0; n2 < 4; ++n2) {
                    o[m][n2][0] *= f0; o[m][n2][1] *= f1;
                    o[m][n2][2] *= f2; o[m][n2][3] *= f3;
                }
            }
        }

        // ---- P -> A-fragment, in-lane ----
        short8 pf[2][2];
        #pragma unroll
        for (int m = 0; m < 2; ++m)
            #pragma unroll
            for (int kk = 0; kk < 2; ++kk)
                #pragma unroll
                for (int e = 0; e < 8; ++e) {
                    union { bf16 b; short s; } u;
                    u.b = __float2bfloat16(sa2[2 * kk + (e >> 2)][m][e & 3]);
                    pf[m][kk][e] = u.s;
                }

        // ---- PV ----
        __builtin_amdgcn_s_setprio(1);
        #pragma unroll
        for (int m = 0; m < 2; ++m)
            #pragma unroll
            for (int n2 = 0; n2 < 4; ++n2)
                #pragma unroll
                for (int kk = 0; kk < 2; ++kk)
                    o[m][n2] = __builtin_amdgcn_mfma_f32_16x16x32_bf16(pf[m][kk], vf[n2][kk], o[m][n2], 0, 0, 0);
        __builtin_amdgcn_s_setprio(0);

        __syncthreads();
    }

    const int b = bh >> 4;
    const int h = bh & 15;
    #pragma unroll
    for (int m = 0; m < 2; ++m) {
        float inv[4];
        #pragma unroll
        for (int j = 0; j < 4; ++j)
            inv[j] = 1.f / __shfl(lrun[m], srcBase + j);
        #pragma unroll
        for (int n2 = 0; n2 < 4; ++n2) {
            const int dim = (h << 6) + n2 * 16 + f;
            #pragma unroll
            for (int j = 0; j < 4; ++j) {
                const int srw = q0 + m * 16 + (g << 2) + j;
                Ctx[(((srw << 2) + b) << 10) + dim] = __float2bfloat16(o[m][n2][j] * inv[j]);
            }
        }
    }
}

// ---------------------------------------------------------------------------
extern "C" void kernel_launch(void* const* d_in, const int* in_sizes, int n_in,
                              void* d_out, int out_size, void* d_ws, size_t ws_size,
                              hipStream_t stream)
{
    const float* query = (const float*)d_in[0];
    const float* wIn   = (const float*)d_in[1];
    const float* bIn   = (const float*)d_in[2];
    const float* wOut  = (const float*)d_in[3];
    const float* bOut  = (const float*)d_in[4];

    const size_t HEADSZ = (size_t)64 * 2048 * 64;   // 8.39M elem
    bf16* Qws = (bf16*)d_ws;
    bf16* Kws = Qws + HEADSZ;
    bf16* Vtw = Kws + HEADSZ;     // transposed [bh][d][s]
    bf16* Ctx = Vtw + HEADSZ;     // also hosts qbf (dead until attn writes it)
    if (ws_size < 4 * HEADSZ * sizeof(bf16)) return;

    // 0) query f32 -> bf16 into the (currently free) Ctx region
    bf16* qbf = Ctx;
    cvt_kernel<<<dim3(4096), 256, 0, stream>>>(query, qbf, 1048576);

    // 1) QKV projection: A = qbf (bf16, GLD_LDS), B = wIn (f32-staged)
    gemm_bt<0, 0, 1><<<dim3(24, 64), 256, 0, stream>>>(qbf, wIn, bIn,
                                                       Qws, Kws, Vtw, 1024, 3072);
    // 2) attention (overwrites Ctx region; qbf is consumed)
    attn_kernel<<<dim3(16, 64), 256, 0, stream>>>(Qws, Kws, Vtw, Ctx);
    // 3) out projection: A = Ctx (bf16), B = wOut (f32-staged), f32 out
    gemm_bt<1, 0, 1><<<dim3(8, 64), 256, 0, stream>>>(Ctx, wOut, bOut,
                                                      d_out, nullptr, nullptr, 1024, 1024);
}